// Round 2
// 1575.836 us; speedup vs baseline: 1.2092x; 1.2092x over previous
//
#include <hip/hip_runtime.h>
#include <hip/hip_bf16.h>
#include <cstdint>
#include <cstddef>

// Problem dims (fixed by the reference)
#define BB 16384
#define DD 1024
#define SS 2048

typedef __attribute__((ext_vector_type(8))) short s8vec;   // 8 bf16 payload
typedef __attribute__((ext_vector_type(4))) short s4vec;
typedef __attribute__((ext_vector_type(4))) float f4vec;

static __device__ __forceinline__ short f2bf(float x) {
  __hip_bfloat16 h = __float2bfloat16(x);
  union { __hip_bfloat16 b; short s; } u; u.b = h; return u.s;
}

static __device__ __forceinline__ float softplus_f(float x) {
  return (x > 20.f) ? x : log1pf(expf(x));
}

// async global->LDS, 16B per lane. LDS dest must be wave-uniform base + lane*16.
static __device__ __forceinline__ void gload16(const void* g, void* l) {
  __builtin_amdgcn_global_load_lds((__attribute__((address_space(1))) void*)g,
                                   (__attribute__((address_space(3))) void*)l,
                                   16, 0, 0);
}

struct EpiParams {
  float* out;          // A1 (EPI 0/1) or h (EPI 3)
  const float* bias;   // b_step / b_in / b_out
  const float* step;   // A1 (EPI 2)
  const float* state;  // fp32 state (EPI 2)
  const float* carry;  // carry_scale (EPI 2)
  const float* ldec;   // log_decay (EPI 2)
  float* out_state;    // d_out + B*D (EPI 2)
  short* xy;           // XY bf16 buffer (EPI 2)
  const float* x;      // x_t fp32 (EPI 3 residual)
};

// raw barrier with compiler-level memory fence (no waitcnt drain — unlike __syncthreads)
#define BAR() do { asm volatile("" ::: "memory"); __builtin_amdgcn_s_barrier(); asm volatile("" ::: "memory"); } while (0)
#define WAIT_LGKM0() do { asm volatile("s_waitcnt lgkmcnt(0)" ::: "memory"); __builtin_amdgcn_sched_barrier(0); } while (0)
#define WAIT_VM(n)   do { asm volatile("s_waitcnt vmcnt(" #n ")" ::: "memory"); __builtin_amdgcn_sched_barrier(0); } while (0)

// 256x256 tile, BK=64, 512 threads = 8 waves (2M x 4N), each wave owns 128x64.
// 8-phase schedule (2 K-tiles per iter), double-buffered 128KB LDS, counted vmcnt.
//
// LDS layout per buffer (32768 shorts): A-half0 | A-half1 | B-half0 | B-half1,
// each half = 128 rows x 64 cols bf16, row stride 128B; 16B slot index is
// XOR-swizzled with (row&7). global_load_lds dest stays LINEAR; the swizzle is
// applied by permuting the per-lane GLOBAL source column (involution), and the
// same XOR on the ds_read side (rule #21: both-sides-or-neither).
//
// Hazard schedule (steady state, iter j; buf0=even tile t0=2j, buf1=odd t1=2j+1):
//   stage issues: t1 halves A0@ph8(prev),A1@ph1,B0@ph2,B1@ph3 -> buf1
//                 t2 halves A0@ph4,A1@ph5,B0@ph6,B1@ph7       -> buf0
//   buf0 reads (ds_read) at ph8(prev),1,2,3; buf0 writes issued ph4..7 — the
//   ph3 trailing barrier orders last read before first write issue. Symmetric
//   for buf1. WAIT_VM(2)@ph4 completes all t1 writes (leaves t2-A0 in flight),
//   then barrier, then first buf1 ds_read — cross-wave ordering via barrier.
//
// vmcnt ledger (per wave, 2 gloads per STAGE):
//   prologue: 5 STAGE = 10 outstanding; WAIT_VM(2) completes t0 (8), leaves t1.A0.
//   ph4: 8 outstanding + STAGE = 10; WAIT_VM(2) completes t1 all 4 halves.
//   ph8: symmetric, completes t2. Never vmcnt(0) in the loop.
template<int EPI>
__global__ __launch_bounds__(512, 2)
void gemm256(const short* __restrict__ A, int lda,
             const short* __restrict__ Bt, int ldb,
             int K, int nbxl, EpiParams ep)
{
  __shared__ short lds0[65536];   // 128 KiB

  const int tid  = threadIdx.x;
  const int lane = tid & 63;
  const int w    = tid >> 6;      // 0..7
  const int wm   = w >> 2;        // 0..1  (M half)
  const int wn   = w & 3;         // 0..3  (N quarter)
  const int frow = lane & 15;
  const int klane = lane >> 4;    // 0..3
  const int swb  = lane & 7;      // row&7 for all fragment rows (row = mult16 + frow)

  // natural mapping: bn fastest => dispatch d -> XCD d%8 pins bn per XCD (B-panel L2 affinity)
  const int lin = blockIdx.x;
  const int bm  = lin >> nbxl;
  const int bn  = lin & ((1 << nbxl) - 1);

  // staging coords: per half-tile each thread does 2x gload16.
  // linear LDS offset (shorts): w*1024 + g*512 + lane*8  <=> row = w*16 + g*8 + (lane>>3), slot = lane&7
  // global source col slot = (lane&7) ^ (row&7) = (lane&7) ^ ((lane>>3)&7)   (pre-swizzle)
  const int rl0    = w * 16 + (lane >> 3);
  const int colsw8 = ((lane & 7) ^ ((lane >> 3) & 7)) * 8;
  const int dOff   = w * 1024 + lane * 8;

  // precomputed global staging bases (one 64-bit addr chain each, saves loop VGPRs)
  const short* gA0 = A  + (size_t)(bm * 256 +       rl0) * lda + colsw8;
  const short* gA1 = A  + (size_t)(bm * 256 + 128 + rl0) * lda + colsw8;
  const short* gB0 = Bt + (size_t)(bn * 256 +       rl0) * ldb + colsw8;
  const short* gB1 = Bt + (size_t)(bn * 256 + 128 + rl0) * ldb + colsw8;
  const int kmax = K - 64;

  auto STAGE = [&](int buf, int h, int kt) {
    const short* g = (h == 0) ? gA0 : (h == 1) ? gA1 : (h == 2) ? gB0 : gB1;
    const int ld = (h < 2) ? lda : ldb;
    int kk = kt * 64; if (kk > kmax) kk = kmax;  // tail: clamped re-stage, data unused
    short* d = &lds0[buf * 32768 + h * 8192 + dOff];
    gload16(g + kk,                 d);
    gload16(g + kk + (size_t)8 * ld, d + 512);
  };

  auto LDA2 = [&](int buf, int frp, s8vec (&a)[2][2]) {   // 4 x ds_read_b128
    const short* base = &lds0[buf * 32768 + wm * 8192];
#pragma unroll
    for (int i = 0; i < 2; i++) {
      const int row = (frp * 2 + i) * 16 + frow;
#pragma unroll
      for (int ks = 0; ks < 2; ks++) {
        const int slot = (ks * 4 + klane) ^ swb;          // swizzled read
        a[i][ks] = *(const s8vec*)&base[row * 64 + slot * 8];
      }
    }
  };

  auto LDB8 = [&](int buf, s8vec (&b)[4][2]) {            // 8 x ds_read_b128 (once per K-tile)
    const short* base = &lds0[buf * 32768 + 16384 + (wn >> 1) * 8192];
#pragma unroll
    for (int fc = 0; fc < 4; fc++) {
      const int row = (wn & 1) * 64 + fc * 16 + frow;
#pragma unroll
      for (int ks = 0; ks < 2; ks++) {
        const int slot = (ks * 4 + klane) ^ swb;
        b[fc][ks] = *(const s8vec*)&base[row * 64 + slot * 8];
      }
    }
  };

  f4vec acc[8][4];
#pragma unroll
  for (int i = 0; i < 8; i++)
#pragma unroll
    for (int j = 0; j < 4; j++) acc[i][j] = (f4vec){0.f, 0.f, 0.f, 0.f};

  s8vec aX[2][2], aY[2][2], bf0[4][2], bf1[4][2];

#define QMFMA(aS, bS, q) do {                                                  \
  _Pragma("unroll") for (int i = 0; i < 2; i++)                                \
  _Pragma("unroll") for (int fc = 0; fc < 4; fc++)                             \
  _Pragma("unroll") for (int ks = 0; ks < 2; ks++)                             \
    acc[(q) * 2 + i][fc] = __builtin_amdgcn_mfma_f32_16x16x32_bf16(            \
        aS[i][ks], bS[fc][ks], acc[(q) * 2 + i][fc], 0, 0, 0);                 \
} while (0)

  // ---- prologue: tile0 fully + tile1 A0; leave t1-A0 in flight
  STAGE(0, 0, 0); STAGE(0, 1, 0); STAGE(0, 2, 0); STAGE(0, 3, 0);
  STAGE(1, 0, 1);
  WAIT_VM(2);
  BAR();
  LDB8(0, bf0);
  LDA2(0, 0, aX);

  const int J = K >> 7;     // 2 K-tiles (128 K) per iter
  for (int j = 0; j < J; ++j) {
    const int t1 = 2 * j + 1, t2 = 2 * j + 2, t3 = 2 * j + 3;
    // ph1: MFMA t0.q0 | read t0.q1 | stage t1.A1
    LDA2(0, 1, aY); STAGE(1, 1, t1);
    BAR(); WAIT_LGKM0();
    __builtin_amdgcn_s_setprio(1); QMFMA(aX, bf0, 0); __builtin_amdgcn_s_setprio(0);
    BAR();
    // ph2
    LDA2(0, 2, aX); STAGE(1, 2, t1);
    BAR(); WAIT_LGKM0();
    __builtin_amdgcn_s_setprio(1); QMFMA(aY, bf0, 1); __builtin_amdgcn_s_setprio(0);
    BAR();
    // ph3
    LDA2(0, 3, aY); STAGE(1, 3, t1);
    BAR(); WAIT_LGKM0();
    __builtin_amdgcn_s_setprio(1); QMFMA(aX, bf0, 2); __builtin_amdgcn_s_setprio(0);
    BAR();
    // ph4: K-tile boundary. stage t2.A0 (buf0 free since ph3), complete t1 writes,
    //      then first reads of buf1. MFMA needs only aY (ready since ph3) — no lgkm wait.
    STAGE(0, 0, t2);
    WAIT_VM(2);
    BAR();
    LDB8(1, bf1); LDA2(1, 0, aX);
    __builtin_amdgcn_s_setprio(1); QMFMA(aY, bf0, 3); __builtin_amdgcn_s_setprio(0);
    BAR();
    // ph5
    LDA2(1, 1, aY); STAGE(0, 1, t2);
    BAR(); WAIT_LGKM0();
    __builtin_amdgcn_s_setprio(1); QMFMA(aX, bf1, 0); __builtin_amdgcn_s_setprio(0);
    BAR();
    // ph6
    LDA2(1, 2, aX); STAGE(0, 2, t2);
    BAR(); WAIT_LGKM0();
    __builtin_amdgcn_s_setprio(1); QMFMA(aY, bf1, 1); __builtin_amdgcn_s_setprio(0);
    BAR();
    // ph7
    LDA2(1, 3, aY); STAGE(0, 3, t2);
    BAR(); WAIT_LGKM0();
    __builtin_amdgcn_s_setprio(1); QMFMA(aX, bf1, 2); __builtin_amdgcn_s_setprio(0);
    BAR();
    // ph8: boundary. stage t3.A0 (buf1 free since ph7), complete t2 writes, first buf0 reads.
    STAGE(1, 0, t3);
    WAIT_VM(2);
    BAR();
    LDB8(0, bf0); LDA2(0, 0, aX);
    __builtin_amdgcn_s_setprio(1); QMFMA(aY, bf1, 3); __builtin_amdgcn_s_setprio(0);
    BAR();
  }
  // drain everything before LDS teardown / register reuse in epilogue
  asm volatile("s_waitcnt vmcnt(0) lgkmcnt(0)" ::: "memory");

  // ---- epilogue. C/D layout per 16x16: col = lane&15, row = (lane>>4)*4 + r (m89-verified)
  const int r0 = bm * 256 + wm * 128 + (lane >> 4) * 4;
  const int c0 = bn * 256 + wn * 64 + (lane & 15);

#pragma unroll
  for (int fr = 0; fr < 8; fr++) {
#pragma unroll
    for (int fc = 0; fc < 4; fc++) {
      const int col = c0 + fc * 16;
#pragma unroll
      for (int r = 0; r < 4; r++) {
        const int row = r0 + fr * 16 + r;
        const float v = acc[fr][fc][r];
        if constexpr (EPI == 0) {            // A1 = softplus(acc + b_step)
          ep.out[(size_t)row * SS + col] = softplus_f(v + ep.bias[col]);
        } else if constexpr (EPI == 1) {     // A1 += 0.1*softplus(acc)
          const size_t idx = (size_t)row * SS + col;
          ep.out[idx] = ep.out[idx] + 0.1f * softplus_f(v);
        } else if constexpr (EPI == 2) {     // fused state update
          const size_t idx = (size_t)row * SS + col;
          const float step = ep.step[idx];
          const float dec  = expf(-step * expf(ep.ldec[col])) * ep.carry[idx];
          const float prop = tanhf(v + ep.bias[col]);
          const float ns   = dec * ep.state[idx] + (1.f - dec) * prop;
          ep.out_state[idx] = ns;
          ep.xy[(size_t)row * 3072 + 1024 + col] = f2bf(ns);
        } else {                             // h = acc + b_out + x
          const size_t idx = (size_t)row * DD + col;
          ep.out[idx] = v + ep.bias[col] + ep.x[idx];
        }
      }
    }
  }
#undef QMFMA
}

// transpose-cast: src fp32 (R,C) -> dst bf16 block at rows [0,C), cols [co, co+R) of ldd-wide buffer
__global__ __launch_bounds__(256)
void tcast(const float* __restrict__ src, int R, int C,
           short* __restrict__ dst, int ldd, int co)
{
  __shared__ float tile[32][33];
  const int c0 = blockIdx.x * 32;
  const int r0 = blockIdx.y * 32;
  const int tx = threadIdx.x;  // 0..31
  const int ty = threadIdx.y;  // 0..7
#pragma unroll
  for (int i = 0; i < 4; i++)
    tile[ty * 4 + i][tx] = src[(size_t)(r0 + ty * 4 + i) * C + c0 + tx];
  __syncthreads();
#pragma unroll
  for (int i = 0; i < 4; i++)
    dst[(size_t)(c0 + ty * 4 + i) * ldd + co + r0 + tx] = f2bf(tile[tx][ty * 4 + i]);
}

__global__ __launch_bounds__(256)
void cast_xc(const float4* __restrict__ x, const float4* __restrict__ c,
             short* __restrict__ Xcat, short* __restrict__ XY)
{
  const size_t i = (size_t)blockIdx.x * 256 + threadIdx.x;
  if (i >= (size_t)BB * (DD / 4)) return;
  const size_t row = i >> 8;           // DD/4 = 256
  const int col4 = (int)(i & 255);
  const float4 xv = x[i];
  const float4 cv = c[i];
  const s4vec xs = { f2bf(xv.x), f2bf(xv.y), f2bf(xv.z), f2bf(xv.w) };
  const s4vec cs = { f2bf(cv.x), f2bf(cv.y), f2bf(cv.z), f2bf(cv.w) };
  *(s4vec*)&Xcat[row * 4096 + col4 * 4]        = xs;
  *(s4vec*)&Xcat[row * 4096 + 1024 + col4 * 4] = cs;
  *(s4vec*)&XY[row * 3072 + col4 * 4]          = xs;
}

__global__ __launch_bounds__(256)
void cast_state(const float4* __restrict__ s, short* __restrict__ Xcat)
{
  const size_t i = (size_t)blockIdx.x * 256 + threadIdx.x;
  if (i >= (size_t)BB * (SS / 4)) return;
  const size_t row = i >> 9;           // SS/4 = 512
  const int col4 = (int)(i & 511);
  const float4 sv = s[i];
  const s4vec ss = { f2bf(sv.x), f2bf(sv.y), f2bf(sv.z), f2bf(sv.w) };
  *(s4vec*)&Xcat[row * 4096 + 2048 + col4 * 4] = ss;
}

// row-wise LayerNorm over D=1024: 256 threads/row, float4 per thread
__global__ __launch_bounds__(256)
void ln_kernel(const float* __restrict__ h, const float* __restrict__ w,
               const float* __restrict__ b, float* __restrict__ out)
{
  const int row = blockIdx.x;
  const int t = threadIdx.x;
  const float4 v = ((const float4*)(h + (size_t)row * DD))[t];
  float s  = v.x + v.y + v.z + v.w;
  float sq = v.x * v.x + v.y * v.y + v.z * v.z + v.w * v.w;
#pragma unroll
  for (int off = 32; off; off >>= 1) {
    s  += __shfl_down(s, off);
    sq += __shfl_down(sq, off);
  }
  __shared__ float ss[4], ssq[4];
  const int lane = t & 63, wv = t >> 6;
  if (lane == 0) { ss[wv] = s; ssq[wv] = sq; }
  __syncthreads();
  const float st  = ss[0] + ss[1] + ss[2] + ss[3];
  const float sqt = ssq[0] + ssq[1] + ssq[2] + ssq[3];
  const float mu  = st * (1.f / (float)DD);
  const float var = sqt * (1.f / (float)DD) - mu * mu;
  const float rstd = rsqrtf(var + 1e-5f);
  const float4 wv4 = ((const float4*)w)[t];
  const float4 bv4 = ((const float4*)b)[t];
  float4 o;
  o.x = (v.x - mu) * rstd * wv4.x + bv4.x;
  o.y = (v.y - mu) * rstd * wv4.y + bv4.y;
  o.z = (v.z - mu) * rstd * wv4.z + bv4.z;
  o.w = (v.w - mu) * rstd * wv4.w + bv4.w;
  ((float4*)(out + (size_t)row * DD))[t] = o;
}

extern "C" void kernel_launch(void* const* d_in, const int* in_sizes, int n_in,
                              void* d_out, int out_size, void* d_ws, size_t ws_size,
                              hipStream_t stream)
{
  const float* x_t    = (const float*)d_in[0];
  const float* state  = (const float*)d_in[1];
  const float* cond   = (const float*)d_in[2];
  const float* carry  = (const float*)d_in[3];
  const float* W_step = (const float*)d_in[4];
  const float* b_step = (const float*)d_in[5];
  const float* W_cstep= (const float*)d_in[6];
  const float* W_in   = (const float*)d_in[7];
  const float* b_in   = (const float*)d_in[8];
  const float* W_cin  = (const float*)d_in[9];
  const float* W_state= (const float*)d_in[10];
  const float* W_out  = (const float*)d_in[11];
  const float* b_out  = (const float*)d_in[12];
  const float* ln_w   = (const float*)d_in[13];
  const float* ln_b   = (const float*)d_in[14];
  const float* ldec   = (const float*)d_in[15];

  char* ws = (char*)d_ws;
  size_t off = 0;
  short* Xcat = (short*)(ws + off); off += (size_t)BB * 4096 * 2;   // 128 MB
  short* XY   = (short*)(ws + off); off += (size_t)BB * 3072 * 2;   //  96 MB
  float* A1   = (float*)(ws + off); off += (size_t)BB * SS * 4;     // 128 MB
  short* WstepT  = (short*)(ws + off); off += (size_t)SS * DD * 2;  //   4 MB
  short* WcstepT = (short*)(ws + off); off += (size_t)SS * DD * 2;  //   4 MB
  short* WcatT   = (short*)(ws + off); off += (size_t)SS * 4096 * 2;//  16 MB
  short* WoutT   = (short*)(ws + off); off += (size_t)DD * 3072 * 2;//   6 MB
  float* hbuf = A1;  // overlay: A1 dead after gemm<2>, h written by gemm<3>

  float* out_ln    = (float*)d_out;
  float* out_state = (float*)d_out + (size_t)BB * DD;

  // 1) activation casts
  cast_xc<<<dim3(BB * (DD / 4) / 256), 256, 0, stream>>>(
      (const float4*)x_t, (const float4*)cond, Xcat, XY);
  cast_state<<<dim3(BB * (SS / 4) / 256), 256, 0, stream>>>(
      (const float4*)state, Xcat);

  // 2) weight transpose-casts: W(K,N) fp32 -> Wt(N,K) bf16
  tcast<<<dim3(SS / 32, DD / 32), dim3(32, 8), 0, stream>>>(W_step, DD, SS, WstepT, DD, 0);
  tcast<<<dim3(SS / 32, DD / 32), dim3(32, 8), 0, stream>>>(W_cstep, DD, SS, WcstepT, DD, 0);
  tcast<<<dim3(SS / 32, DD / 32), dim3(32, 8), 0, stream>>>(W_in,   DD, SS, WcatT, 4096, 0);
  tcast<<<dim3(SS / 32, DD / 32), dim3(32, 8), 0, stream>>>(W_cin,  DD, SS, WcatT, 4096, 1024);
  tcast<<<dim3(SS / 32, SS / 32), dim3(32, 8), 0, stream>>>(W_state, SS, SS, WcatT, 4096, 2048);
  tcast<<<dim3(DD / 32, 3072 / 32), dim3(32, 8), 0, stream>>>(W_out, 3072, DD, WoutT, 3072, 0);

  const int nwgS = (BB / 256) * (SS / 256);  // 64*8 = 512
  const int nwgD = (BB / 256) * (DD / 256);  // 64*4 = 256

  // 3) A1 = softplus(x @ W_step + b_step)
  EpiParams p1{}; p1.out = A1; p1.bias = b_step;
  gemm256<0><<<dim3(nwgS), 512, 0, stream>>>(Xcat, 4096, WstepT, DD, 1024, 3, p1);

  // 4) A1 += 0.1*softplus(cond @ W_cstep)
  EpiParams p2{}; p2.out = A1;
  gemm256<1><<<dim3(nwgS), 512, 0, stream>>>(Xcat + 1024, 4096, WcstepT, DD, 1024, 3, p2);

  // 5) P = [x|cond|state] @ [W_in;W_cin;W_state]; fused state update epilogue
  EpiParams p3{};
  p3.bias = b_in; p3.step = A1; p3.state = state; p3.carry = carry;
  p3.ldec = ldec; p3.out_state = out_state; p3.xy = XY;
  gemm256<2><<<dim3(nwgS), 512, 0, stream>>>(Xcat, 4096, WcatT, 4096, 4096, 3, p3);

  // 6) h = [x|new_state] @ W_out + b_out + x
  EpiParams p4{}; p4.out = hbuf; p4.bias = b_out; p4.x = x_t;
  gemm256<3><<<dim3(nwgD), 512, 0, stream>>>(XY, 3072, WoutT, 3072, 3072, 2, p4);

  // 7) LayerNorm
  ln_kernel<<<dim3(BB), 256, 0, stream>>>(hbuf, ln_w, ln_b, out_ln);
}